// Round 8
// baseline (625.487 us; speedup 1.0000x reference)
//
#include <hip/hip_runtime.h>

// Problem constants (from reference): N=100000, H=20000, E=1600000, D=64, L=3, F=256
#define HYP 20000
#define NLAYER 3
// Bucket-sort geometry: ids fit 15 bits (H=20000) / 17 bits (N=100000).
#define NB_H 313
#define NB_N 391
#define PT 4096

typedef __attribute__((ext_vector_type(8))) short short8;
typedef __attribute__((ext_vector_type(4))) float floatx4;

static __device__ __forceinline__ unsigned short f2bf(float f){
  union { float f; unsigned u; } v; v.f = f;
  unsigned r = v.u + 0x7FFF + ((v.u >> 16) & 1);
  return (unsigned short)(r >> 16);
}

// ---- CSR build, stage 1: global bucket histogram (LDS-staged) ----
__global__ __launch_bounds__(256) void k_hist(const int* __restrict__ src,
    const int* __restrict__ dst, int E, int* __restrict__ bh, int* __restrict__ bn){
  __shared__ int lh[NB_H + NB_N];
  int tid = threadIdx.x;
  for (int i = tid; i < NB_H + NB_N; i += 256) lh[i] = 0;
  __syncthreads();
  for (int i = blockIdx.x*256 + tid; i < E; i += gridDim.x*256){
    atomicAdd(&lh[dst[i] >> 6], 1);
    atomicAdd(&lh[NB_H + (src[i] >> 8)], 1);
  }
  __syncthreads();
  for (int i = tid; i < NB_H; i += 256) if (lh[i]) atomicAdd(&bh[i], lh[i]);
  for (int i = tid; i < NB_N; i += 256) if (lh[NB_H+i]) atomicAdd(&bn[i], lh[NB_H+i]);
}

// ---- stage 2: exclusive scan of bucket counts -> bucket starts + cursors ----
__global__ __launch_bounds__(256) void k_bscan(const int* __restrict__ bh,
    const int* __restrict__ bn, int* __restrict__ bstart_h, int* __restrict__ gcur_h,
    int* __restrict__ bstart_n, int* __restrict__ gcur_n){
  __shared__ int ssc[4];
  __shared__ int scarry;
  int tid = threadIdx.x, lane = tid & 63, wv = tid >> 6;
  if (tid == 0) scarry = 0;
  __syncthreads();
  for (int base = 0; base < NB_H; base += 256){
    int i = base + tid; int v = (i < NB_H) ? bh[i] : 0; int x = v;
    #pragma unroll
    for (int o = 1; o < 64; o <<= 1){ int t = __shfl_up(x,o,64); if (lane >= o) x += t; }
    if (lane == 63) ssc[wv] = x;
    __syncthreads();
    int add = (wv>0?ssc[0]:0)+(wv>1?ssc[1]:0)+(wv>2?ssc[2]:0);
    int c = scarry;
    if (i < NB_H){ int ex = c + add + x - v; bstart_h[i] = ex; gcur_h[i] = ex; }
    __syncthreads();
    if (tid == 255) scarry = c + ssc[0]+ssc[1]+ssc[2]+ssc[3];
    __syncthreads();
  }
  if (tid == 0){ bstart_h[NB_H] = scarry; scarry = 0; }
  __syncthreads();
  for (int base = 0; base < NB_N; base += 256){
    int i = base + tid; int v = (i < NB_N) ? bn[i] : 0; int x = v;
    #pragma unroll
    for (int o = 1; o < 64; o <<= 1){ int t = __shfl_up(x,o,64); if (lane >= o) x += t; }
    if (lane == 63) ssc[wv] = x;
    __syncthreads();
    int add = (wv>0?ssc[0]:0)+(wv>1?ssc[1]:0)+(wv>2?ssc[2]:0);
    int c = scarry;
    if (i < NB_N){ int ex = c + add + x - v; bstart_n[i] = ex; gcur_n[i] = ex; }
    __syncthreads();
    if (tid == 255) scarry = c + ssc[0]+ssc[1]+ssc[2]+ssc[3];
    __syncthreads();
  }
  if (tid == 0) bstart_n[NB_N] = scarry;
}

// ---- stage 3: LDS-staged radix partition into bucket-contiguous entry buffer ----
__global__ __launch_bounds__(256) void k_partition(const int* __restrict__ keys,
    const int* __restrict__ pays, int E, int keyshift, int nb,
    int* __restrict__ gcur, unsigned* __restrict__ Ebuf){
  __shared__ unsigned sst[PT];
  __shared__ int lh[NB_N], lpre[NB_N], gb[NB_N];
  __shared__ int ssc[4];
  __shared__ int scarry;
  int tid = threadIdx.x, lane = tid & 63, wv = tid >> 6;
  int base = blockIdx.x*PT;
  int m = min(PT, E - base);
  for (int i = tid; i < nb; i += 256) lh[i] = 0;
  if (tid == 0) scarry = 0;
  __syncthreads();
  unsigned en[16]; int rk[16];
  #pragma unroll
  for (int j = 0; j < 16; ++j){
    int i = base + j*256 + tid;
    if (i < E){
      unsigned k = (unsigned)keys[i], p = (unsigned)pays[i];
      en[j] = (k << keyshift) | p;
      rk[j] = atomicAdd(&lh[en[j] >> 23], 1);
    } else { en[j] = 0; rk[j] = -1; }
  }
  __syncthreads();
  for (int b2 = 0; b2 < nb; b2 += 256){
    int i = b2 + tid; int v = (i < nb) ? lh[i] : 0; int x = v;
    #pragma unroll
    for (int o = 1; o < 64; o <<= 1){ int t = __shfl_up(x,o,64); if (lane >= o) x += t; }
    if (lane == 63) ssc[wv] = x;
    __syncthreads();
    int add = (wv>0?ssc[0]:0)+(wv>1?ssc[1]:0)+(wv>2?ssc[2]:0);
    int c = scarry;
    if (i < nb) lpre[i] = c + add + x - v;
    __syncthreads();
    if (tid == 255) scarry = c + ssc[0]+ssc[1]+ssc[2]+ssc[3];
    __syncthreads();
  }
  for (int i = tid; i < nb; i += 256) gb[i] = atomicAdd(&gcur[i], lh[i]);
  #pragma unroll
  for (int j = 0; j < 16; ++j){
    if (rk[j] >= 0){
      int bk = en[j] >> 23;
      sst[lpre[bk] + rk[j]] = en[j];
    }
  }
  __syncthreads();
  for (int j = tid; j < m; j += 256){
    unsigned e = sst[j];
    int bk = e >> 23;
    Ebuf[gb[bk] + (j - lpre[bk])] = e;
  }
}

// ---- stage 4: per-bucket CSR build ----
__global__ __launch_bounds__(256) void k_build(const unsigned* __restrict__ Ebuf,
    const int* __restrict__ bstart, int keyshift, int ipb, int paymask, int limit,
    int* __restrict__ off, float* __restrict__ isv, int* __restrict__ csr){
  __shared__ int lcnt[256], lpre2[256], lcur[256];
  int tid = threadIdx.x, lane = tid & 63, wv = tid >> 6;
  int b = blockIdx.x;
  int base = bstart[b], m = bstart[b+1] - base;
  for (int i = tid; i < ipb; i += 256) lcnt[i] = 0;
  __syncthreads();
  for (int i = tid; i < m; i += 256){
    unsigned e = Ebuf[base + i];
    atomicAdd(&lcnt[(e >> keyshift) & (ipb-1)], 1);
  }
  __syncthreads();
  if (wv == 0){
    int carry = 0;
    for (int c = 0; c < ipb; c += 64){
      int li = c + lane;
      int v = lcnt[li]; int x = v;
      #pragma unroll
      for (int o = 1; o < 64; o <<= 1){ int t = __shfl_up(x,o,64); if (lane >= o) x += t; }
      int ex = carry + x - v;
      int id = b*ipb + li;
      if (id <= limit) off[id] = base + ex;
      if (id < limit) isv[id] = rsqrtf((float)(v > 0 ? v : 1));
      lpre2[li] = ex;
      carry += __shfl(x, 63, 64);
    }
  }
  for (int i = tid; i < ipb; i += 256) lcur[i] = 0;
  __syncthreads();
  for (int i = tid; i < m; i += 256){
    unsigned e = Ebuf[base + i];
    int li = (e >> keyshift) & (ipb-1);
    int pos = base + lpre2[li] + atomicAdd(&lcur[li], 1);
    csr[pos] = (int)(e & (unsigned)paymask);
  }
}

// Pre-scale + bf16-convert node features for layer-0 h-gather
__global__ void k_prescale(const float* __restrict__ x, const float* __restrict__ isn,
                           unsigned short* __restrict__ xb, int nrows){
  int i = blockIdx.x*blockDim.x + threadIdx.x;
  int st = gridDim.x*blockDim.x;
  int tot = nrows*64;
  for (; i < tot; i += st){ xb[i] = f2bf(x[i]*isn[i >> 6]); }
}

// Convert all weights to bf16, TRANSPOSED layouts (B-fragments become contiguous
// 16B global loads -> no LDS weight staging needed in compute kernels).
__global__ void k_cvtall(const float* __restrict__ W1, const float* __restrict__ W2,
                         const float* __restrict__ Wa, const float* __restrict__ Wb,
                         const float* __restrict__ Wo,
                         unsigned short* __restrict__ W1T, unsigned short* __restrict__ W2T,
                         unsigned short* __restrict__ WaT, unsigned short* __restrict__ WbT,
                         unsigned short* __restrict__ WoT){
  int st = gridDim.x*blockDim.x;
  int t0 = blockIdx.x*blockDim.x + threadIdx.x;
  for (int j = t0; j < NLAYER*16384; j += st){
    int l = j >> 14, n = (j >> 6) & 255, k = j & 63;
    W1T[j] = f2bf(W1[l*16384 + k*256 + n]);
  }
  for (int j = t0; j < NLAYER*16384; j += st){
    int l = j >> 14, o = (j >> 8) & 63, kk = j & 255;
    W2T[j] = f2bf(W2[l*16384 + kk*64 + o]);
  }
  for (int j = t0; j < NLAYER*4096; j += st){
    int l = j >> 12, n = (j >> 6) & 63, k = j & 63;
    WaT[j] = f2bf(Wa[l*4096 + k*64 + n]);
  }
  for (int j = t0; j < NLAYER*4096; j += st){
    int l = j >> 12, n = (j >> 6) & 63, k = j & 63;
    WbT[j] = f2bf(Wb[l*4096 + k*64 + n]);
  }
  for (int j = t0; j < 4096; j += st){
    int n = (j >> 6) & 63, k = j & 63;
    WoT[j] = f2bf(Wo[k*64 + n]);
  }
}

#define ACC8(u) \
  a0 += __uint_as_float(u.x << 16); a1 += __uint_as_float(u.x & 0xFFFF0000u); \
  a2 += __uint_as_float(u.y << 16); a3 += __uint_as_float(u.y & 0xFFFF0000u); \
  a4 += __uint_as_float(u.z << 16); a5 += __uint_as_float(u.z & 0xFFFF0000u); \
  a6 += __uint_as_float(u.w << 16); a7 += __uint_as_float(u.w & 0xFFFF0000u);

// Gather: wave per row, 4x unrolled, bf16 in/out, fp32 accumulate,
// butterfly-combine 8 edge slots (xor 8/16/32).
__global__ __launch_bounds__(256) void k_gather8(const unsigned short* __restrict__ feat,
    const int* __restrict__ csr, const int* __restrict__ off,
    unsigned short* __restrict__ agg, int nrows){
  int lane = threadIdx.x & 63, wvi = threadIdx.x >> 6;
  int g = lane >> 3;
  int ch = (lane & 7) * 8;
  int r = blockIdx.x*4 + wvi, stride = gridDim.x*4;
  for (; r < nrows; r += stride){
    int b = off[r], e = off[r+1];
    float a0=0,a1=0,a2=0,a3=0,a4=0,a5=0,a6=0,a7=0;
    int t = b;
    for (; t + 32 <= e; t += 32){
      int s0 = csr[t + g];
      int s1 = csr[t + 8 + g];
      int s2 = csr[t + 16 + g];
      int s3 = csr[t + 24 + g];
      uint4 u0 = *(const uint4*)&feat[(size_t)s0*64 + ch];
      uint4 u1 = *(const uint4*)&feat[(size_t)s1*64 + ch];
      uint4 u2 = *(const uint4*)&feat[(size_t)s2*64 + ch];
      uint4 u3 = *(const uint4*)&feat[(size_t)s3*64 + ch];
      ACC8(u0); ACC8(u1); ACC8(u2); ACC8(u3);
    }
    for (; t + 16 <= e; t += 16){
      int s0 = csr[t + g];
      int s1 = csr[t + 8 + g];
      uint4 u0 = *(const uint4*)&feat[(size_t)s0*64 + ch];
      uint4 u1 = *(const uint4*)&feat[(size_t)s1*64 + ch];
      ACC8(u0); ACC8(u1);
    }
    for (; t < e; t += 8){
      int idx = t + g;
      bool valid = idx < e;
      int s = csr[valid ? idx : b];
      uint4 u = *(const uint4*)&feat[(size_t)s*64 + ch];
      if (!valid){ u.x = 0; u.y = 0; u.z = 0; u.w = 0; }
      ACC8(u);
    }
    #pragma unroll
    for (int o = 8; o <= 32; o <<= 1){
      a0 += __shfl_xor(a0,o,64); a1 += __shfl_xor(a1,o,64);
      a2 += __shfl_xor(a2,o,64); a3 += __shfl_xor(a3,o,64);
      a4 += __shfl_xor(a4,o,64); a5 += __shfl_xor(a5,o,64);
      a6 += __shfl_xor(a6,o,64); a7 += __shfl_xor(a7,o,64);
    }
    if (g == 0){
      uint4 w;
      w.x = (unsigned)f2bf(a0) | ((unsigned)f2bf(a1) << 16);
      w.y = (unsigned)f2bf(a2) | ((unsigned)f2bf(a3) << 16);
      w.z = (unsigned)f2bf(a4) | ((unsigned)f2bf(a5) << 16);
      w.w = (unsigned)f2bf(a6) | ((unsigned)f2bf(a7) << 16);
      *(uint4*)&agg[(size_t)r*64 + ch] = w;
    }
  }
}

// MFMA mmA, no LDS weights / no barriers: B-frags direct from global (L2-hot).
__global__ __launch_bounds__(256) void k_mmA(const unsigned short* __restrict__ aggb,
    const unsigned short* __restrict__ WaT, const float* __restrict__ bias,
    const float* __restrict__ ihy, unsigned short* __restrict__ ouths, int nrows){
  int tid = threadIdx.x;
  int lane = tid & 63, w = tid >> 6;
  int quad = lane >> 4, n16 = lane & 15;
  int rowbase = blockIdx.x*64 + w*16;
  int arow = min(rowbase + n16, nrows-1);
  short8 a0 = *(const short8*)&aggb[(size_t)arow*64 + quad*8];
  short8 a1 = *(const short8*)&aggb[(size_t)arow*64 + 32 + quad*8];
  float ih[4];
  #pragma unroll
  for (int r = 0; r < 4; ++r) ih[r] = ihy[min(rowbase + quad*4 + r, nrows-1)];
  #pragma unroll
  for (int ot = 0; ot < 4; ++ot){
    floatx4 c = (floatx4){0.f,0.f,0.f,0.f};
    short8 b0 = *(const short8*)&WaT[(ot*16+n16)*64 + quad*8];
    short8 b1 = *(const short8*)&WaT[(ot*16+n16)*64 + 32 + quad*8];
    c = __builtin_amdgcn_mfma_f32_16x16x32_bf16(a0, b0, c, 0, 0, 0);
    c = __builtin_amdgcn_mfma_f32_16x16x32_bf16(a1, b1, c, 0, 0, 0);
    float bl = bias[ot*16 + n16];
    #pragma unroll
    for (int r = 0; r < 4; ++r){
      int rr = rowbase + quad*4 + r;
      if (rr < nrows)
        ouths[(size_t)rr*64 + ot*16 + n16] = f2bf(fmaf(c[r], ih[r], bl) * ih[r]);
    }
  }
}

// Fused per-node pipeline, 64-row tile, NO weight LDS, NO barriers:
// P = LN1(hin + (aggh@Wb)*is_n + bb); Out = LN2(P + relu(P@W1+b1)@W2 + b2);
// Qs = bf16(Out*is_n). B-fragments load directly from transposed global weights.
__global__ __launch_bounds__(256) void k_fused(
    const unsigned short* __restrict__ aggb,
    const unsigned short* __restrict__ WbT,    // [64 n][64 k]
    const float* __restrict__ bbg,
    const float* __restrict__ isn,
    const float* __restrict__ hin,
    const float* __restrict__ g1v, const float* __restrict__ be1v,
    const unsigned short* __restrict__ W1T,    // [256 n][64 k]
    const float* __restrict__ b1g,
    const unsigned short* __restrict__ W2T,    // [64 o][256 kk]
    const float* __restrict__ b2g,
    const float* __restrict__ g2v, const float* __restrict__ be2v,
    float* __restrict__ Outp, unsigned short* __restrict__ Qs, int nrows)
{
  __shared__ unsigned short sPH[4*16*72];      // per-wave C->A round-trip scratch
  int tid = threadIdx.x;
  int lane = tid & 63, w = tid >> 6;
  int quad = lane >> 4, n16 = lane & 15;
  int rowbase = blockIdx.x*64 + w*16;

  // mmB: aggh @ Wb
  int arow = min(rowbase + n16, nrows-1);
  short8 a0 = *(const short8*)&aggb[(size_t)arow*64 + quad*8];
  short8 a1 = *(const short8*)&aggb[(size_t)arow*64 + 32 + quad*8];
  float pP[4][4];
  float isr[4];
  #pragma unroll
  for (int r = 0; r < 4; ++r) isr[r] = isn[min(rowbase + quad*4 + r, nrows-1)];
  #pragma unroll
  for (int ot = 0; ot < 4; ++ot){
    floatx4 c = (floatx4){0.f,0.f,0.f,0.f};
    short8 b0 = *(const short8*)&WbT[(ot*16+n16)*64 + quad*8];
    short8 b1 = *(const short8*)&WbT[(ot*16+n16)*64 + 32 + quad*8];
    c = __builtin_amdgcn_mfma_f32_16x16x32_bf16(a0, b0, c, 0, 0, 0);
    c = __builtin_amdgcn_mfma_f32_16x16x32_bf16(a1, b1, c, 0, 0, 0);
    float bb = bbg[ot*16 + n16];
    #pragma unroll
    for (int r = 0; r < 4; ++r){
      int rr = min(rowbase + quad*4 + r, nrows-1);
      pP[ot][r] = fmaf(c[r], isr[r], bb) + hin[(size_t)rr*64 + ot*16 + n16];
    }
  }
  // LN1
  {
    float gl[4], bl[4];
    #pragma unroll
    for (int ot = 0; ot < 4; ++ot){ gl[ot] = g1v[ot*16+n16]; bl[ot] = be1v[ot*16+n16]; }
    #pragma unroll
    for (int r = 0; r < 4; ++r){
      float sv = (pP[0][r] + pP[1][r]) + (pP[2][r] + pP[3][r]);
      float q = fmaf(pP[0][r], pP[0][r], pP[1][r]*pP[1][r]) +
                fmaf(pP[2][r], pP[2][r], pP[3][r]*pP[3][r]);
      #pragma unroll
      for (int o = 8; o >= 1; o >>= 1){
        sv += __shfl_xor(sv, o, 64);
        q  += __shfl_xor(q, o, 64);
      }
      float mu = sv*(1.f/64.f);
      float var = fmaf(-mu, mu, q*(1.f/64.f));
      float rs = rsqrtf(var + 1e-5f);
      #pragma unroll
      for (int ot = 0; ot < 4; ++ot)
        pP[ot][r] = fmaf((pP[ot][r]-mu)*rs, gl[ot], bl[ot]);
    }
  }
  // C-layout -> A-layout via per-wave LDS round trip
  unsigned short* myP = &sPH[w*16*72];
  #pragma unroll
  for (int ot = 0; ot < 4; ++ot)
    #pragma unroll
    for (int r = 0; r < 4; ++r)
      myP[(quad*4 + r)*72 + ot*16 + n16] = f2bf(pP[ot][r]);
  short8 p0 = *(const short8*)&myP[n16*72 + quad*8];
  short8 p1 = *(const short8*)&myP[n16*72 + 32 + quad*8];

  // FFN: 8 chunks of 32 hidden; weights straight from global
  floatx4 acc2[4];
  #pragma unroll
  for (int t = 0; t < 4; ++t) acc2[t] = (floatx4){0.f,0.f,0.f,0.f};
  unsigned short* myHc = &sPH[w*16*72];

  for (int ck = 0; ck < 8; ++ck){
    #pragma unroll
    for (int nt = 0; nt < 2; ++nt){
      int nn = ck*32 + nt*16 + n16;
      floatx4 c = (floatx4){0.f,0.f,0.f,0.f};
      short8 b0 = *(const short8*)&W1T[nn*64 + quad*8];
      short8 b1f = *(const short8*)&W1T[nn*64 + 32 + quad*8];
      c = __builtin_amdgcn_mfma_f32_16x16x32_bf16(p0, b0, c, 0, 0, 0);
      c = __builtin_amdgcn_mfma_f32_16x16x32_bf16(p1, b1f, c, 0, 0, 0);
      float bb = b1g[nn];
      #pragma unroll
      for (int r = 0; r < 4; ++r){
        float h = fmaxf(c[r] + bb, 0.f);
        myHc[(quad*4 + r)*40 + nt*16 + n16] = f2bf(h);
      }
    }
    short8 a2 = *(const short8*)&myHc[n16*40 + quad*8];
    #pragma unroll
    for (int ot = 0; ot < 4; ++ot){
      short8 b2f = *(const short8*)&W2T[(ot*16 + n16)*256 + ck*32 + quad*8];
      acc2[ot] = __builtin_amdgcn_mfma_f32_16x16x32_bf16(a2, b2f, acc2[ot], 0, 0, 0);
    }
  }

  // epilogue-2: + b2 + P residual, LN2, write Out fp32 + Qs bf16
  float pre[4][4];
  #pragma unroll
  for (int ot = 0; ot < 4; ++ot){
    float b2c = b2g[ot*16 + n16];
    #pragma unroll
    for (int r = 0; r < 4; ++r)
      pre[ot][r] = acc2[ot][r] + b2c + pP[ot][r];
  }
  float gl[4], bel[4];
  #pragma unroll
  for (int ot = 0; ot < 4; ++ot){ gl[ot] = g2v[ot*16 + n16]; bel[ot] = be2v[ot*16 + n16]; }
  #pragma unroll
  for (int r = 0; r < 4; ++r){
    float sv = (pre[0][r] + pre[1][r]) + (pre[2][r] + pre[3][r]);
    float q = fmaf(pre[0][r], pre[0][r], pre[1][r]*pre[1][r]) +
              fmaf(pre[2][r], pre[2][r], pre[3][r]*pre[3][r]);
    #pragma unroll
    for (int o = 8; o >= 1; o >>= 1){
      sv += __shfl_xor(sv, o, 64);
      q  += __shfl_xor(q, o, 64);
    }
    float mu = sv*(1.f/64.f);
    float var = fmaf(-mu, mu, q*(1.f/64.f));
    float rs = rsqrtf(var + 1e-5f);
    int rr = rowbase + quad*4 + r;
    if (rr < nrows){
      float isr2 = isn[rr];
      #pragma unroll
      for (int ot = 0; ot < 4; ++ot){
        float ov = fmaf((pre[ot][r]-mu)*rs, gl[ot], bel[ot]);
        Outp[(size_t)rr*64 + ot*16 + n16] = ov;
        Qs[(size_t)rr*64 + ot*16 + n16] = f2bf(ov * isr2);
      }
    }
  }
}

// MFMA final, no LDS: out = LN(Q, gF, bF) @ Wo + bo
__global__ __launch_bounds__(256) void k_final(const float* __restrict__ Q,
    const unsigned short* __restrict__ WoT, const float* __restrict__ bog,
    const float* __restrict__ gF, const float* __restrict__ bF,
    float* __restrict__ out, int nrows){
  int tid = threadIdx.x;
  int lane = tid & 63, w = tid >> 6;
  int quad = lane >> 4, n16 = lane & 15;
  int rowbase = blockIdx.x*64 + w*16;
  int arow = min(rowbase + n16, nrows-1);
  float4 q0 = *(const float4*)&Q[(size_t)arow*64 + quad*8];
  float4 q1 = *(const float4*)&Q[(size_t)arow*64 + quad*8 + 4];
  float4 q2 = *(const float4*)&Q[(size_t)arow*64 + 32 + quad*8];
  float4 q3 = *(const float4*)&Q[(size_t)arow*64 + 32 + quad*8 + 4];
  float s = (q0.x+q0.y+q0.z+q0.w) + (q1.x+q1.y+q1.z+q1.w)
          + (q2.x+q2.y+q2.z+q2.w) + (q3.x+q3.y+q3.z+q3.w);
  float qq = (q0.x*q0.x+q0.y*q0.y+q0.z*q0.z+q0.w*q0.w)
           + (q1.x*q1.x+q1.y*q1.y+q1.z*q1.z+q1.w*q1.w)
           + (q2.x*q2.x+q2.y*q2.y+q2.z*q2.z+q2.w*q2.w)
           + (q3.x*q3.x+q3.y*q3.y+q3.z*q3.z+q3.w*q3.w);
  s += __shfl_xor(s, 16, 64);  qq += __shfl_xor(qq, 16, 64);
  s += __shfl_xor(s, 32, 64);  qq += __shfl_xor(qq, 32, 64);
  float mu = s*(1.f/64.f);
  float var = fmaf(-mu, mu, qq*(1.f/64.f));
  float rs = rsqrtf(var + 1e-5f);
  float4 g0 = *(const float4*)&gF[quad*8];
  float4 g1 = *(const float4*)&gF[quad*8 + 4];
  float4 g2 = *(const float4*)&gF[32 + quad*8];
  float4 g3 = *(const float4*)&gF[32 + quad*8 + 4];
  float4 f0 = *(const float4*)&bF[quad*8];
  float4 f1 = *(const float4*)&bF[quad*8 + 4];
  float4 f2 = *(const float4*)&bF[32 + quad*8];
  float4 f3 = *(const float4*)&bF[32 + quad*8 + 4];
  short8 a0, a1;
  a0[0]=f2bf(fmaf((q0.x-mu)*rs, g0.x, f0.x)); a0[1]=f2bf(fmaf((q0.y-mu)*rs, g0.y, f0.y));
  a0[2]=f2bf(fmaf((q0.z-mu)*rs, g0.z, f0.z)); a0[3]=f2bf(fmaf((q0.w-mu)*rs, g0.w, f0.w));
  a0[4]=f2bf(fmaf((q1.x-mu)*rs, g1.x, f1.x)); a0[5]=f2bf(fmaf((q1.y-mu)*rs, g1.y, f1.y));
  a0[6]=f2bf(fmaf((q1.z-mu)*rs, g1.z, f1.z)); a0[7]=f2bf(fmaf((q1.w-mu)*rs, g1.w, f1.w));
  a1[0]=f2bf(fmaf((q2.x-mu)*rs, g2.x, f2.x)); a1[1]=f2bf(fmaf((q2.y-mu)*rs, g2.y, f2.y));
  a1[2]=f2bf(fmaf((q2.z-mu)*rs, g2.z, f2.z)); a1[3]=f2bf(fmaf((q2.w-mu)*rs, g2.w, f2.w));
  a1[4]=f2bf(fmaf((q3.x-mu)*rs, g3.x, f3.x)); a1[5]=f2bf(fmaf((q3.y-mu)*rs, g3.y, f3.y));
  a1[6]=f2bf(fmaf((q3.z-mu)*rs, g3.z, f3.z)); a1[7]=f2bf(fmaf((q3.w-mu)*rs, g3.w, f3.w));
  #pragma unroll
  for (int ot = 0; ot < 4; ++ot){
    floatx4 c = (floatx4){0.f,0.f,0.f,0.f};
    short8 b0 = *(const short8*)&WoT[(ot*16+n16)*64 + quad*8];
    short8 b1 = *(const short8*)&WoT[(ot*16+n16)*64 + 32 + quad*8];
    c = __builtin_amdgcn_mfma_f32_16x16x32_bf16(a0, b0, c, 0, 0, 0);
    c = __builtin_amdgcn_mfma_f32_16x16x32_bf16(a1, b1, c, 0, 0, 0);
    float bol = bog[ot*16 + n16];
    #pragma unroll
    for (int r = 0; r < 4; ++r){
      int rr = rowbase + quad*4 + r;
      if (rr < nrows) out[(size_t)rr*64 + ot*16 + n16] = c[r] + bol;
    }
  }
}

extern "C" void kernel_launch(void* const* d_in, const int* in_sizes, int n_in,
                              void* d_out, int out_size, void* d_ws, size_t ws_size,
                              hipStream_t stream){
  const float* nf   = (const float*)d_in[0];
  const int*   esrc = (const int*)d_in[1];
  const int*   edst = (const int*)d_in[2];
  const float* Wn2h = (const float*)d_in[4];
  const float* bn2h = (const float*)d_in[5];
  const float* Wh2n = (const float*)d_in[6];
  const float* bh2n = (const float*)d_in[7];
  const float* W1   = (const float*)d_in[8];
  const float* b1   = (const float*)d_in[9];
  const float* W2   = (const float*)d_in[10];
  const float* b2   = (const float*)d_in[11];
  const float* g1   = (const float*)d_in[12];
  const float* be1  = (const float*)d_in[13];
  const float* g2   = (const float*)d_in[14];
  const float* be2  = (const float*)d_in[15];
  const float* gF   = (const float*)d_in[16];
  const float* bF   = (const float*)d_in[17];
  const float* Wo   = (const float*)d_in[18];
  const float* bo   = (const float*)d_in[19];
  const int N = in_sizes[0] / 64;
  const int E = in_sizes[1];
  const int H = HYP;
  float* out = (float*)d_out;

  char* w = (char*)d_ws;
  auto carve = [&](size_t bytes) -> char* {
    char* p = w; w += (bytes + 255) & ~(size_t)255; return p;
  };
  int* bh = (int*)carve((size_t)(NB_H + NB_N)*4);
  int* bn = bh + NB_H;
  int* bstart_h = (int*)carve((size_t)(NB_H+1)*4);
  int* gcur_h   = (int*)carve((size_t)NB_H*4);
  int* bstart_n = (int*)carve((size_t)(NB_N+1)*4);
  int* gcur_n   = (int*)carve((size_t)NB_N*4);
  unsigned* Ebuf_h = (unsigned*)carve((size_t)E*4);
  unsigned* Ebuf_n = (unsigned*)carve((size_t)E*4);
  int*   off_h = (int*)carve((size_t)(H+1)*4);
  int*   off_n = (int*)carve((size_t)(N+1)*4);
  float* is_h  = (float*)carve((size_t)H*4);
  float* is_n  = (float*)carve((size_t)N*4);
  int*   csr_h = (int*)carve((size_t)E*4);
  int*   csr_n = (int*)carve((size_t)E*4);
  unsigned short* aggxb = (unsigned short*)carve((size_t)H*64*2);
  unsigned short* agghb = (unsigned short*)carve((size_t)N*64*2);
  float* Qb    = (float*)carve((size_t)N*64*4);
  unsigned short* hhsb = (unsigned short*)carve((size_t)H*64*2);
  unsigned short* xb0  = (unsigned short*)carve((size_t)N*64*2);
  unsigned short* Qs   = (unsigned short*)carve((size_t)N*64*2);
  unsigned short* W1g16 = (unsigned short*)carve((size_t)NLAYER*64*256*2);
  unsigned short* W2g16 = (unsigned short*)carve((size_t)NLAYER*256*64*2);
  unsigned short* Wag16 = (unsigned short*)carve((size_t)NLAYER*4096*2);
  unsigned short* Wbg16 = (unsigned short*)carve((size_t)NLAYER*4096*2);
  unsigned short* Wog16 = (unsigned short*)carve((size_t)4096*2);

  hipMemsetAsync(bh, 0, (size_t)(NB_H + NB_N)*4, stream);
  k_cvtall<<<96, 256, 0, stream>>>(W1, W2, Wn2h, Wh2n, Wo,
                                   W1g16, W2g16, Wag16, Wbg16, Wog16);
  k_hist<<<512, 256, 0, stream>>>(esrc, edst, E, bh, bn);
  k_bscan<<<1, 256, 0, stream>>>(bh, bn, bstart_h, gcur_h, bstart_n, gcur_n);
  k_partition<<<(E + PT - 1)/PT, 256, 0, stream>>>(edst, esrc, E, 17, NB_H, gcur_h, Ebuf_h);
  k_partition<<<(E + PT - 1)/PT, 256, 0, stream>>>(esrc, edst, E, 15, NB_N, gcur_n, Ebuf_n);
  k_build<<<NB_H, 256, 0, stream>>>(Ebuf_h, bstart_h, 17, 64, 0x1FFFF, H, off_h, is_h, csr_h);
  k_build<<<NB_N, 256, 0, stream>>>(Ebuf_n, bstart_n, 15, 256, 0x7FFF, N, off_n, is_n, csr_n);
  k_prescale<<<4096, 256, 0, stream>>>(nf, is_n, xb0, N);

  const int NB64 = (N + 63)/64;
  const int HB64 = (H + 63)/64;
  for (int l = 0; l < NLAYER; ++l){
    const float* hin = (l == 0) ? nf : Qb;
    const unsigned short* hsrc = (l == 0) ? xb0 : Qs;
    k_gather8<<<2048, 256, 0, stream>>>(hsrc, csr_h, off_h, aggxb, H);
    k_mmA<<<HB64, 256, 0, stream>>>(aggxb, Wag16 + l*4096, bn2h + l*64, is_h, hhsb, H);
    k_gather8<<<2048, 256, 0, stream>>>(hhsb, csr_n, off_n, agghb, N);
    k_fused<<<NB64, 256, 0, stream>>>(agghb, Wbg16 + l*4096, bh2n + l*64, is_n, hin,
                                      g1 + l*64, be1 + l*64,
                                      W1g16 + l*64*256, b1 + l*256,
                                      W2g16 + l*256*64, b2 + l*64,
                                      g2 + l*64, be2 + l*64, Qb, Qs, N);
  }
  k_final<<<NB64, 256, 0, stream>>>(Qb, Wog16, bo, gF, bF, out, N);
}

// Round 9
// 550.432 us; speedup vs baseline: 1.1364x; 1.1364x over previous
//
#include <hip/hip_runtime.h>

// Problem constants (from reference): N=100000, H=20000, E=1600000, D=64, L=3, F=256
#define HYP 20000
#define NLAYER 3
// Bucket-sort geometry: ids fit 15 bits (H=20000) / 17 bits (N=100000).
#define NB_H 313
#define NB_N 391
#define PT 4096

typedef __attribute__((ext_vector_type(8))) short short8;
typedef __attribute__((ext_vector_type(4))) float floatx4;

static __device__ __forceinline__ unsigned short f2bf(float f){
  union { float f; unsigned u; } v; v.f = f;
  unsigned r = v.u + 0x7FFF + ((v.u >> 16) & 1);
  return (unsigned short)(r >> 16);
}

// ---- CSR build, stage 1: global bucket histogram (LDS-staged) ----
__global__ __launch_bounds__(256) void k_hist(const int* __restrict__ src,
    const int* __restrict__ dst, int E, int* __restrict__ bh, int* __restrict__ bn){
  __shared__ int lh[NB_H + NB_N];
  int tid = threadIdx.x;
  for (int i = tid; i < NB_H + NB_N; i += 256) lh[i] = 0;
  __syncthreads();
  for (int i = blockIdx.x*256 + tid; i < E; i += gridDim.x*256){
    atomicAdd(&lh[dst[i] >> 6], 1);
    atomicAdd(&lh[NB_H + (src[i] >> 8)], 1);
  }
  __syncthreads();
  for (int i = tid; i < NB_H; i += 256) if (lh[i]) atomicAdd(&bh[i], lh[i]);
  for (int i = tid; i < NB_N; i += 256) if (lh[NB_H+i]) atomicAdd(&bn[i], lh[NB_H+i]);
}

// ---- stage 2: exclusive scan of bucket counts -> bucket starts + cursors ----
__global__ __launch_bounds__(256) void k_bscan(const int* __restrict__ bh,
    const int* __restrict__ bn, int* __restrict__ bstart_h, int* __restrict__ gcur_h,
    int* __restrict__ bstart_n, int* __restrict__ gcur_n){
  __shared__ int ssc[4];
  __shared__ int scarry;
  int tid = threadIdx.x, lane = tid & 63, wv = tid >> 6;
  if (tid == 0) scarry = 0;
  __syncthreads();
  for (int base = 0; base < NB_H; base += 256){
    int i = base + tid; int v = (i < NB_H) ? bh[i] : 0; int x = v;
    #pragma unroll
    for (int o = 1; o < 64; o <<= 1){ int t = __shfl_up(x,o,64); if (lane >= o) x += t; }
    if (lane == 63) ssc[wv] = x;
    __syncthreads();
    int add = (wv>0?ssc[0]:0)+(wv>1?ssc[1]:0)+(wv>2?ssc[2]:0);
    int c = scarry;
    if (i < NB_H){ int ex = c + add + x - v; bstart_h[i] = ex; gcur_h[i] = ex; }
    __syncthreads();
    if (tid == 255) scarry = c + ssc[0]+ssc[1]+ssc[2]+ssc[3];
    __syncthreads();
  }
  if (tid == 0){ bstart_h[NB_H] = scarry; scarry = 0; }
  __syncthreads();
  for (int base = 0; base < NB_N; base += 256){
    int i = base + tid; int v = (i < NB_N) ? bn[i] : 0; int x = v;
    #pragma unroll
    for (int o = 1; o < 64; o <<= 1){ int t = __shfl_up(x,o,64); if (lane >= o) x += t; }
    if (lane == 63) ssc[wv] = x;
    __syncthreads();
    int add = (wv>0?ssc[0]:0)+(wv>1?ssc[1]:0)+(wv>2?ssc[2]:0);
    int c = scarry;
    if (i < NB_N){ int ex = c + add + x - v; bstart_n[i] = ex; gcur_n[i] = ex; }
    __syncthreads();
    if (tid == 255) scarry = c + ssc[0]+ssc[1]+ssc[2]+ssc[3];
    __syncthreads();
  }
  if (tid == 0) bstart_n[NB_N] = scarry;
}

// ---- stage 3: LDS-staged radix partition into bucket-contiguous entry buffer ----
__global__ __launch_bounds__(256) void k_partition(const int* __restrict__ keys,
    const int* __restrict__ pays, int E, int keyshift, int nb,
    int* __restrict__ gcur, unsigned* __restrict__ Ebuf){
  __shared__ unsigned sst[PT];
  __shared__ int lh[NB_N], lpre[NB_N], gb[NB_N];
  __shared__ int ssc[4];
  __shared__ int scarry;
  int tid = threadIdx.x, lane = tid & 63, wv = tid >> 6;
  int base = blockIdx.x*PT;
  int m = min(PT, E - base);
  for (int i = tid; i < nb; i += 256) lh[i] = 0;
  if (tid == 0) scarry = 0;
  __syncthreads();
  unsigned en[16]; int rk[16];
  #pragma unroll
  for (int j = 0; j < 16; ++j){
    int i = base + j*256 + tid;
    if (i < E){
      unsigned k = (unsigned)keys[i], p = (unsigned)pays[i];
      en[j] = (k << keyshift) | p;
      rk[j] = atomicAdd(&lh[en[j] >> 23], 1);
    } else { en[j] = 0; rk[j] = -1; }
  }
  __syncthreads();
  for (int b2 = 0; b2 < nb; b2 += 256){
    int i = b2 + tid; int v = (i < nb) ? lh[i] : 0; int x = v;
    #pragma unroll
    for (int o = 1; o < 64; o <<= 1){ int t = __shfl_up(x,o,64); if (lane >= o) x += t; }
    if (lane == 63) ssc[wv] = x;
    __syncthreads();
    int add = (wv>0?ssc[0]:0)+(wv>1?ssc[1]:0)+(wv>2?ssc[2]:0);
    int c = scarry;
    if (i < nb) lpre[i] = c + add + x - v;
    __syncthreads();
    if (tid == 255) scarry = c + ssc[0]+ssc[1]+ssc[2]+ssc[3];
    __syncthreads();
  }
  for (int i = tid; i < nb; i += 256) gb[i] = atomicAdd(&gcur[i], lh[i]);
  #pragma unroll
  for (int j = 0; j < 16; ++j){
    if (rk[j] >= 0){
      int bk = en[j] >> 23;
      sst[lpre[bk] + rk[j]] = en[j];
    }
  }
  __syncthreads();
  for (int j = tid; j < m; j += 256){
    unsigned e = sst[j];
    int bk = e >> 23;
    Ebuf[gb[bk] + (j - lpre[bk])] = e;
  }
}

// ---- stage 4: per-bucket CSR build ----
__global__ __launch_bounds__(256) void k_build(const unsigned* __restrict__ Ebuf,
    const int* __restrict__ bstart, int keyshift, int ipb, int paymask, int limit,
    int* __restrict__ off, float* __restrict__ isv, int* __restrict__ csr){
  __shared__ int lcnt[256], lpre2[256], lcur[256];
  int tid = threadIdx.x, lane = tid & 63, wv = tid >> 6;
  int b = blockIdx.x;
  int base = bstart[b], m = bstart[b+1] - base;
  for (int i = tid; i < ipb; i += 256) lcnt[i] = 0;
  __syncthreads();
  for (int i = tid; i < m; i += 256){
    unsigned e = Ebuf[base + i];
    atomicAdd(&lcnt[(e >> keyshift) & (ipb-1)], 1);
  }
  __syncthreads();
  if (wv == 0){
    int carry = 0;
    for (int c = 0; c < ipb; c += 64){
      int li = c + lane;
      int v = lcnt[li]; int x = v;
      #pragma unroll
      for (int o = 1; o < 64; o <<= 1){ int t = __shfl_up(x,o,64); if (lane >= o) x += t; }
      int ex = carry + x - v;
      int id = b*ipb + li;
      if (id <= limit) off[id] = base + ex;
      if (id < limit) isv[id] = rsqrtf((float)(v > 0 ? v : 1));
      lpre2[li] = ex;
      carry += __shfl(x, 63, 64);
    }
  }
  for (int i = tid; i < ipb; i += 256) lcur[i] = 0;
  __syncthreads();
  for (int i = tid; i < m; i += 256){
    unsigned e = Ebuf[base + i];
    int li = (e >> keyshift) & (ipb-1);
    int pos = base + lpre2[li] + atomicAdd(&lcur[li], 1);
    csr[pos] = (int)(e & (unsigned)paymask);
  }
}

// Pre-scale + bf16-convert node features for layer-0 h-gather
__global__ void k_prescale(const float* __restrict__ x, const float* __restrict__ isn,
                           unsigned short* __restrict__ xb, int nrows){
  int i = blockIdx.x*blockDim.x + threadIdx.x;
  int st = gridDim.x*blockDim.x;
  int tot = nrows*64;
  for (; i < tot; i += st){ xb[i] = f2bf(x[i]*isn[i >> 6]); }
}

// Convert all weights to bf16, TRANSPOSED layouts.
__global__ void k_cvtall(const float* __restrict__ W1, const float* __restrict__ W2,
                         const float* __restrict__ Wa, const float* __restrict__ Wb,
                         const float* __restrict__ Wo,
                         unsigned short* __restrict__ W1T, unsigned short* __restrict__ W2T,
                         unsigned short* __restrict__ WaT, unsigned short* __restrict__ WbT,
                         unsigned short* __restrict__ WoT){
  int st = gridDim.x*blockDim.x;
  int t0 = blockIdx.x*blockDim.x + threadIdx.x;
  for (int j = t0; j < NLAYER*16384; j += st){
    int l = j >> 14, n = (j >> 6) & 255, k = j & 63;
    W1T[j] = f2bf(W1[l*16384 + k*256 + n]);
  }
  for (int j = t0; j < NLAYER*16384; j += st){
    int l = j >> 14, o = (j >> 8) & 63, kk = j & 255;
    W2T[j] = f2bf(W2[l*16384 + kk*64 + o]);
  }
  for (int j = t0; j < NLAYER*4096; j += st){
    int l = j >> 12, n = (j >> 6) & 63, k = j & 63;
    WaT[j] = f2bf(Wa[l*4096 + k*64 + n]);
  }
  for (int j = t0; j < NLAYER*4096; j += st){
    int l = j >> 12, n = (j >> 6) & 63, k = j & 63;
    WbT[j] = f2bf(Wb[l*4096 + k*64 + n]);
  }
  for (int j = t0; j < 4096; j += st){
    int n = (j >> 6) & 63, k = j & 63;
    WoT[j] = f2bf(Wo[k*64 + n]);
  }
}

#define ACC8(u) \
  a0 += __uint_as_float(u.x << 16); a1 += __uint_as_float(u.x & 0xFFFF0000u); \
  a2 += __uint_as_float(u.y << 16); a3 += __uint_as_float(u.y & 0xFFFF0000u); \
  a4 += __uint_as_float(u.z << 16); a5 += __uint_as_float(u.z & 0xFFFF0000u); \
  a6 += __uint_as_float(u.w << 16); a7 += __uint_as_float(u.w & 0xFFFF0000u);

// Gather: wave per row, 4x unrolled, bf16 in/out, fp32 accumulate,
// butterfly-combine 8 edge slots (xor 8/16/32).
__global__ __launch_bounds__(256) void k_gather8(const unsigned short* __restrict__ feat,
    const int* __restrict__ csr, const int* __restrict__ off,
    unsigned short* __restrict__ agg, int nrows){
  int lane = threadIdx.x & 63, wvi = threadIdx.x >> 6;
  int g = lane >> 3;
  int ch = (lane & 7) * 8;
  int r = blockIdx.x*4 + wvi, stride = gridDim.x*4;
  for (; r < nrows; r += stride){
    int b = off[r], e = off[r+1];
    float a0=0,a1=0,a2=0,a3=0,a4=0,a5=0,a6=0,a7=0;
    int t = b;
    for (; t + 32 <= e; t += 32){
      int s0 = csr[t + g];
      int s1 = csr[t + 8 + g];
      int s2 = csr[t + 16 + g];
      int s3 = csr[t + 24 + g];
      uint4 u0 = *(const uint4*)&feat[(size_t)s0*64 + ch];
      uint4 u1 = *(const uint4*)&feat[(size_t)s1*64 + ch];
      uint4 u2 = *(const uint4*)&feat[(size_t)s2*64 + ch];
      uint4 u3 = *(const uint4*)&feat[(size_t)s3*64 + ch];
      ACC8(u0); ACC8(u1); ACC8(u2); ACC8(u3);
    }
    for (; t + 16 <= e; t += 16){
      int s0 = csr[t + g];
      int s1 = csr[t + 8 + g];
      uint4 u0 = *(const uint4*)&feat[(size_t)s0*64 + ch];
      uint4 u1 = *(const uint4*)&feat[(size_t)s1*64 + ch];
      ACC8(u0); ACC8(u1);
    }
    for (; t < e; t += 8){
      int idx = t + g;
      bool valid = idx < e;
      int s = csr[valid ? idx : b];
      uint4 u = *(const uint4*)&feat[(size_t)s*64 + ch];
      if (!valid){ u.x = 0; u.y = 0; u.z = 0; u.w = 0; }
      ACC8(u);
    }
    #pragma unroll
    for (int o = 8; o <= 32; o <<= 1){
      a0 += __shfl_xor(a0,o,64); a1 += __shfl_xor(a1,o,64);
      a2 += __shfl_xor(a2,o,64); a3 += __shfl_xor(a3,o,64);
      a4 += __shfl_xor(a4,o,64); a5 += __shfl_xor(a5,o,64);
      a6 += __shfl_xor(a6,o,64); a7 += __shfl_xor(a7,o,64);
    }
    if (g == 0){
      uint4 w;
      w.x = (unsigned)f2bf(a0) | ((unsigned)f2bf(a1) << 16);
      w.y = (unsigned)f2bf(a2) | ((unsigned)f2bf(a3) << 16);
      w.z = (unsigned)f2bf(a4) | ((unsigned)f2bf(a5) << 16);
      w.w = (unsigned)f2bf(a6) | ((unsigned)f2bf(a7) << 16);
      *(uint4*)&agg[(size_t)r*64 + ch] = w;
    }
  }
}

// MFMA mmA (global weights; Wa is tiny and L2-hot — measured neutral vs LDS).
__global__ __launch_bounds__(256) void k_mmA(const unsigned short* __restrict__ aggb,
    const unsigned short* __restrict__ WaT, const float* __restrict__ bias,
    const float* __restrict__ ihy, unsigned short* __restrict__ ouths, int nrows){
  int tid = threadIdx.x;
  int lane = tid & 63, w = tid >> 6;
  int quad = lane >> 4, n16 = lane & 15;
  int rowbase = blockIdx.x*64 + w*16;
  int arow = min(rowbase + n16, nrows-1);
  short8 a0 = *(const short8*)&aggb[(size_t)arow*64 + quad*8];
  short8 a1 = *(const short8*)&aggb[(size_t)arow*64 + 32 + quad*8];
  float ih[4];
  #pragma unroll
  for (int r = 0; r < 4; ++r) ih[r] = ihy[min(rowbase + quad*4 + r, nrows-1)];
  #pragma unroll
  for (int ot = 0; ot < 4; ++ot){
    floatx4 c = (floatx4){0.f,0.f,0.f,0.f};
    short8 b0 = *(const short8*)&WaT[(ot*16+n16)*64 + quad*8];
    short8 b1 = *(const short8*)&WaT[(ot*16+n16)*64 + 32 + quad*8];
    c = __builtin_amdgcn_mfma_f32_16x16x32_bf16(a0, b0, c, 0, 0, 0);
    c = __builtin_amdgcn_mfma_f32_16x16x32_bf16(a1, b1, c, 0, 0, 0);
    float bl = bias[ot*16 + n16];
    #pragma unroll
    for (int r = 0; r < 4; ++r){
      int rr = rowbase + quad*4 + r;
      if (rr < nrows)
        ouths[(size_t)rr*64 + ot*16 + n16] = f2bf(fmaf(c[r], ih[r], bl) * ih[r]);
    }
  }
}

// PERSISTENT fused per-node pipeline: 1024-thread blocks (16 waves), grid=256.
// Stage ALL weights (Wb+W1+W2, 80KB) into LDS ONCE, single barrier, then each
// wave grid-strides over 16-row tiles with zero further synchronization.
// P = LN1(hin + (aggh@Wb)*is_n + bb); Out = LN2(P + relu(P@W1+b1)@W2 + b2);
// Qs = bf16(Out*is_n).
__global__ __launch_bounds__(1024, 1) void k_fused(
    const unsigned short* __restrict__ aggb,
    const unsigned short* __restrict__ WbT,    // [64 n][64 k]
    const float* __restrict__ bbg,
    const float* __restrict__ isn,
    const float* __restrict__ hin,
    const float* __restrict__ g1v, const float* __restrict__ be1v,
    const unsigned short* __restrict__ W1T,    // [256 n][64 k]
    const float* __restrict__ b1g,
    const unsigned short* __restrict__ W2T,    // [64 o][256 kk]
    const float* __restrict__ b2g,
    const float* __restrict__ g2v, const float* __restrict__ be2v,
    float* __restrict__ Outp, unsigned short* __restrict__ Qs, int nrows)
{
  __shared__ unsigned short sWb[64*72];        // 9.2 KB
  __shared__ unsigned short sW1[256*72];       // 36.9 KB
  __shared__ unsigned short sW2[64*264];       // 33.8 KB
  __shared__ unsigned short sPH[16*16*72];     // 36.9 KB per-wave scratch
  int tid = threadIdx.x;
  int lane = tid & 63, wv = tid >> 6;          // 16 waves
  int quad = lane >> 4, n16 = lane & 15;

  // ---- one-time cooperative weight staging (contiguous 16B chunks) ----
  for (int idx = tid; idx < 64*8; idx += 1024){
    int row = idx >> 3, kc = (idx & 7)*8;
    *(uint4*)&sWb[row*72 + kc] = *(const uint4*)&WbT[row*64 + kc];
  }
  for (int idx = tid; idx < 256*8; idx += 1024){
    int row = idx >> 3, kc = (idx & 7)*8;
    *(uint4*)&sW1[row*72 + kc] = *(const uint4*)&W1T[row*64 + kc];
  }
  for (int idx = tid; idx < 64*32; idx += 1024){
    int row = idx >> 5, kc = (idx & 31)*8;
    *(uint4*)&sW2[row*264 + kc] = *(const uint4*)&W2T[row*256 + kc];
  }
  __syncthreads();   // the only barrier

  unsigned short* myP = &sPH[wv*16*72];
  int ntiles = (nrows + 15) >> 4;

  for (int tile = blockIdx.x*16 + wv; tile < ntiles; tile += 256*16){
    int rowbase = tile << 4;
    // mmB: aggh @ Wb
    int arow = min(rowbase + n16, nrows-1);
    short8 a0 = *(const short8*)&aggb[(size_t)arow*64 + quad*8];
    short8 a1 = *(const short8*)&aggb[(size_t)arow*64 + 32 + quad*8];
    float pP[4][4];
    float isr[4];
    #pragma unroll
    for (int r = 0; r < 4; ++r) isr[r] = isn[min(rowbase + quad*4 + r, nrows-1)];
    #pragma unroll
    for (int ot = 0; ot < 4; ++ot){
      floatx4 c = (floatx4){0.f,0.f,0.f,0.f};
      short8 b0 = *(const short8*)&sWb[(ot*16+n16)*72 + quad*8];
      short8 b1 = *(const short8*)&sWb[(ot*16+n16)*72 + 32 + quad*8];
      c = __builtin_amdgcn_mfma_f32_16x16x32_bf16(a0, b0, c, 0, 0, 0);
      c = __builtin_amdgcn_mfma_f32_16x16x32_bf16(a1, b1, c, 0, 0, 0);
      float bb = bbg[ot*16 + n16];
      #pragma unroll
      for (int r = 0; r < 4; ++r){
        int rr = min(rowbase + quad*4 + r, nrows-1);
        pP[ot][r] = fmaf(c[r], isr[r], bb) + hin[(size_t)rr*64 + ot*16 + n16];
      }
    }
    // LN1
    {
      float gl[4], bl[4];
      #pragma unroll
      for (int ot = 0; ot < 4; ++ot){ gl[ot] = g1v[ot*16+n16]; bl[ot] = be1v[ot*16+n16]; }
      #pragma unroll
      for (int r = 0; r < 4; ++r){
        float sv = (pP[0][r] + pP[1][r]) + (pP[2][r] + pP[3][r]);
        float q = fmaf(pP[0][r], pP[0][r], pP[1][r]*pP[1][r]) +
                  fmaf(pP[2][r], pP[2][r], pP[3][r]*pP[3][r]);
        #pragma unroll
        for (int o = 8; o >= 1; o >>= 1){
          sv += __shfl_xor(sv, o, 64);
          q  += __shfl_xor(q, o, 64);
        }
        float mu = sv*(1.f/64.f);
        float var = fmaf(-mu, mu, q*(1.f/64.f));
        float rs = rsqrtf(var + 1e-5f);
        #pragma unroll
        for (int ot = 0; ot < 4; ++ot)
          pP[ot][r] = fmaf((pP[ot][r]-mu)*rs, gl[ot], bl[ot]);
      }
    }
    // C-layout -> A-layout via per-wave LDS round trip (same-wave, no barrier)
    #pragma unroll
    for (int ot = 0; ot < 4; ++ot)
      #pragma unroll
      for (int r = 0; r < 4; ++r)
        myP[(quad*4 + r)*72 + ot*16 + n16] = f2bf(pP[ot][r]);
    short8 p0 = *(const short8*)&myP[n16*72 + quad*8];
    short8 p1 = *(const short8*)&myP[n16*72 + 32 + quad*8];

    // FFN: 8 chunks of 32 hidden; weights from LDS
    floatx4 acc2[4];
    #pragma unroll
    for (int t = 0; t < 4; ++t) acc2[t] = (floatx4){0.f,0.f,0.f,0.f};

    for (int ck = 0; ck < 8; ++ck){
      #pragma unroll
      for (int nt = 0; nt < 2; ++nt){
        int nn = ck*32 + nt*16 + n16;
        floatx4 c = (floatx4){0.f,0.f,0.f,0.f};
        short8 b0 = *(const short8*)&sW1[nn*72 + quad*8];
        short8 b1f = *(const short8*)&sW1[nn*72 + 32 + quad*8];
        c = __builtin_amdgcn_mfma_f32_16x16x32_bf16(p0, b0, c, 0, 0, 0);
        c = __builtin_amdgcn_mfma_f32_16x16x32_bf16(p1, b1f, c, 0, 0, 0);
        float bb = b1g[nn];
        #pragma unroll
        for (int r = 0; r < 4; ++r){
          float h = fmaxf(c[r] + bb, 0.f);
          myP[(quad*4 + r)*40 + nt*16 + n16] = f2bf(h);
        }
      }
      short8 a2 = *(const short8*)&myP[n16*40 + quad*8];
      #pragma unroll
      for (int ot = 0; ot < 4; ++ot){
        short8 b2f = *(const short8*)&sW2[(ot*16 + n16)*264 + ck*32 + quad*8];
        acc2[ot] = __builtin_amdgcn_mfma_f32_16x16x32_bf16(a2, b2f, acc2[ot], 0, 0, 0);
      }
    }

    // epilogue-2: + b2 + P residual, LN2, write Out fp32 + Qs bf16
    float pre[4][4];
    #pragma unroll
    for (int ot = 0; ot < 4; ++ot){
      float b2c = b2g[ot*16 + n16];
      #pragma unroll
      for (int r = 0; r < 4; ++r)
        pre[ot][r] = acc2[ot][r] + b2c + pP[ot][r];
    }
    float gl[4], bel[4];
    #pragma unroll
    for (int ot = 0; ot < 4; ++ot){ gl[ot] = g2v[ot*16 + n16]; bel[ot] = be2v[ot*16 + n16]; }
    #pragma unroll
    for (int r = 0; r < 4; ++r){
      float sv = (pre[0][r] + pre[1][r]) + (pre[2][r] + pre[3][r]);
      float q = fmaf(pre[0][r], pre[0][r], pre[1][r]*pre[1][r]) +
                fmaf(pre[2][r], pre[2][r], pre[3][r]*pre[3][r]);
      #pragma unroll
      for (int o = 8; o >= 1; o >>= 1){
        sv += __shfl_xor(sv, o, 64);
        q  += __shfl_xor(q, o, 64);
      }
      float mu = sv*(1.f/64.f);
      float var = fmaf(-mu, mu, q*(1.f/64.f));
      float rs = rsqrtf(var + 1e-5f);
      int rr = rowbase + quad*4 + r;
      if (rr < nrows){
        float isr2 = isn[rr];
        #pragma unroll
        for (int ot = 0; ot < 4; ++ot){
          float ov = fmaf((pre[ot][r]-mu)*rs, gl[ot], bel[ot]);
          Outp[(size_t)rr*64 + ot*16 + n16] = ov;
          Qs[(size_t)rr*64 + ot*16 + n16] = f2bf(ov * isr2);
        }
      }
    }
  }
}

// MFMA final (global weights): out = LN(Q, gF, bF) @ Wo + bo
__global__ __launch_bounds__(256) void k_final(const float* __restrict__ Q,
    const unsigned short* __restrict__ WoT, const float* __restrict__ bog,
    const float* __restrict__ gF, const float* __restrict__ bF,
    float* __restrict__ out, int nrows){
  int tid = threadIdx.x;
  int lane = tid & 63, w = tid >> 6;
  int quad = lane >> 4, n16 = lane & 15;
  int rowbase = blockIdx.x*64 + w*16;
  int arow = min(rowbase + n16, nrows-1);
  float4 q0 = *(const float4*)&Q[(size_t)arow*64 + quad*8];
  float4 q1 = *(const float4*)&Q[(size_t)arow*64 + quad*8 + 4];
  float4 q2 = *(const float4*)&Q[(size_t)arow*64 + 32 + quad*8];
  float4 q3 = *(const float4*)&Q[(size_t)arow*64 + 32 + quad*8 + 4];
  float s = (q0.x+q0.y+q0.z+q0.w) + (q1.x+q1.y+q1.z+q1.w)
          + (q2.x+q2.y+q2.z+q2.w) + (q3.x+q3.y+q3.z+q3.w);
  float qq = (q0.x*q0.x+q0.y*q0.y+q0.z*q0.z+q0.w*q0.w)
           + (q1.x*q1.x+q1.y*q1.y+q1.z*q1.z+q1.w*q1.w)
           + (q2.x*q2.x+q2.y*q2.y+q2.z*q2.z+q2.w*q2.w)
           + (q3.x*q3.x+q3.y*q3.y+q3.z*q3.z+q3.w*q3.w);
  s += __shfl_xor(s, 16, 64);  qq += __shfl_xor(qq, 16, 64);
  s += __shfl_xor(s, 32, 64);  qq += __shfl_xor(qq, 32, 64);
  float mu = s*(1.f/64.f);
  float var = fmaf(-mu, mu, qq*(1.f/64.f));
  float rs = rsqrtf(var + 1e-5f);
  float4 g0 = *(const float4*)&gF[quad*8];
  float4 g1 = *(const float4*)&gF[quad*8 + 4];
  float4 g2 = *(const float4*)&gF[32 + quad*8];
  float4 g3 = *(const float4*)&gF[32 + quad*8 + 4];
  float4 f0 = *(const float4*)&bF[quad*8];
  float4 f1 = *(const float4*)&bF[quad*8 + 4];
  float4 f2 = *(const float4*)&bF[32 + quad*8];
  float4 f3 = *(const float4*)&bF[32 + quad*8 + 4];
  short8 a0, a1;
  a0[0]=f2bf(fmaf((q0.x-mu)*rs, g0.x, f0.x)); a0[1]=f2bf(fmaf((q0.y-mu)*rs, g0.y, f0.y));
  a0[2]=f2bf(fmaf((q0.z-mu)*rs, g0.z, f0.z)); a0[3]=f2bf(fmaf((q0.w-mu)*rs, g0.w, f0.w));
  a0[4]=f2bf(fmaf((q1.x-mu)*rs, g1.x, f1.x)); a0[5]=f2bf(fmaf((q1.y-mu)*rs, g1.y, f1.y));
  a0[6]=f2bf(fmaf((q1.z-mu)*rs, g1.z, f1.z)); a0[7]=f2bf(fmaf((q1.w-mu)*rs, g1.w, f1.w));
  a1[0]=f2bf(fmaf((q2.x-mu)*rs, g2.x, f2.x)); a1[1]=f2bf(fmaf((q2.y-mu)*rs, g2.y, f2.y));
  a1[2]=f2bf(fmaf((q2.z-mu)*rs, g2.z, f2.z)); a1[3]=f2bf(fmaf((q2.w-mu)*rs, g2.w, f2.w));
  a1[4]=f2bf(fmaf((q3.x-mu)*rs, g3.x, f3.x)); a1[5]=f2bf(fmaf((q3.y-mu)*rs, g3.y, f3.y));
  a1[6]=f2bf(fmaf((q3.z-mu)*rs, g3.z, f3.z)); a1[7]=f2bf(fmaf((q3.w-mu)*rs, g3.w, f3.w));
  #pragma unroll
  for (int ot = 0; ot < 4; ++ot){
    floatx4 c = (floatx4){0.f,0.f,0.f,0.f};
    short8 b0 = *(const short8*)&WoT[(ot*16+n16)*64 + quad*8];
    short8 b1 = *(const short8*)&WoT[(ot*16+n16)*64 + 32 + quad*8];
    c = __builtin_amdgcn_mfma_f32_16x16x32_bf16(a0, b0, c, 0, 0, 0);
    c = __builtin_amdgcn_mfma_f32_16x16x32_bf16(a1, b1, c, 0, 0, 0);
    float bol = bog[ot*16 + n16];
    #pragma unroll
    for (int r = 0; r < 4; ++r){
      int rr = rowbase + quad*4 + r;
      if (rr < nrows) out[(size_t)rr*64 + ot*16 + n16] = c[r] + bol;
    }
  }
}

extern "C" void kernel_launch(void* const* d_in, const int* in_sizes, int n_in,
                              void* d_out, int out_size, void* d_ws, size_t ws_size,
                              hipStream_t stream){
  const float* nf   = (const float*)d_in[0];
  const int*   esrc = (const int*)d_in[1];
  const int*   edst = (const int*)d_in[2];
  const float* Wn2h = (const float*)d_in[4];
  const float* bn2h = (const float*)d_in[5];
  const float* Wh2n = (const float*)d_in[6];
  const float* bh2n = (const float*)d_in[7];
  const float* W1   = (const float*)d_in[8];
  const float* b1   = (const float*)d_in[9];
  const float* W2   = (const float*)d_in[10];
  const float* b2   = (const float*)d_in[11];
  const float* g1   = (const float*)d_in[12];
  const float* be1  = (const float*)d_in[13];
  const float* g2   = (const float*)d_in[14];
  const float* be2  = (const float*)d_in[15];
  const float* gF   = (const float*)d_in[16];
  const float* bF   = (const float*)d_in[17];
  const float* Wo   = (const float*)d_in[18];
  const float* bo   = (const float*)d_in[19];
  const int N = in_sizes[0] / 64;
  const int E = in_sizes[1];
  const int H = HYP;
  float* out = (float*)d_out;

  char* w = (char*)d_ws;
  auto carve = [&](size_t bytes) -> char* {
    char* p = w; w += (bytes + 255) & ~(size_t)255; return p;
  };
  int* bh = (int*)carve((size_t)(NB_H + NB_N)*4);
  int* bn = bh + NB_H;
  int* bstart_h = (int*)carve((size_t)(NB_H+1)*4);
  int* gcur_h   = (int*)carve((size_t)NB_H*4);
  int* bstart_n = (int*)carve((size_t)(NB_N+1)*4);
  int* gcur_n   = (int*)carve((size_t)NB_N*4);
  unsigned* Ebuf_h = (unsigned*)carve((size_t)E*4);
  unsigned* Ebuf_n = (unsigned*)carve((size_t)E*4);
  int*   off_h = (int*)carve((size_t)(H+1)*4);
  int*   off_n = (int*)carve((size_t)(N+1)*4);
  float* is_h  = (float*)carve((size_t)H*4);
  float* is_n  = (float*)carve((size_t)N*4);
  int*   csr_h = (int*)carve((size_t)E*4);
  int*   csr_n = (int*)carve((size_t)E*4);
  unsigned short* aggxb = (unsigned short*)carve((size_t)H*64*2);
  unsigned short* agghb = (unsigned short*)carve((size_t)N*64*2);
  float* Qb    = (float*)carve((size_t)N*64*4);
  unsigned short* hhsb = (unsigned short*)carve((size_t)H*64*2);
  unsigned short* xb0  = (unsigned short*)carve((size_t)N*64*2);
  unsigned short* Qs   = (unsigned short*)carve((size_t)N*64*2);
  unsigned short* W1g16 = (unsigned short*)carve((size_t)NLAYER*64*256*2);
  unsigned short* W2g16 = (unsigned short*)carve((size_t)NLAYER*256*64*2);
  unsigned short* Wag16 = (unsigned short*)carve((size_t)NLAYER*4096*2);
  unsigned short* Wbg16 = (unsigned short*)carve((size_t)NLAYER*4096*2);
  unsigned short* Wog16 = (unsigned short*)carve((size_t)4096*2);

  hipMemsetAsync(bh, 0, (size_t)(NB_H + NB_N)*4, stream);
  k_cvtall<<<96, 256, 0, stream>>>(W1, W2, Wn2h, Wh2n, Wo,
                                   W1g16, W2g16, Wag16, Wbg16, Wog16);
  k_hist<<<512, 256, 0, stream>>>(esrc, edst, E, bh, bn);
  k_bscan<<<1, 256, 0, stream>>>(bh, bn, bstart_h, gcur_h, bstart_n, gcur_n);
  k_partition<<<(E + PT - 1)/PT, 256, 0, stream>>>(edst, esrc, E, 17, NB_H, gcur_h, Ebuf_h);
  k_partition<<<(E + PT - 1)/PT, 256, 0, stream>>>(esrc, edst, E, 15, NB_N, gcur_n, Ebuf_n);
  k_build<<<NB_H, 256, 0, stream>>>(Ebuf_h, bstart_h, 17, 64, 0x1FFFF, H, off_h, is_h, csr_h);
  k_build<<<NB_N, 256, 0, stream>>>(Ebuf_n, bstart_n, 15, 256, 0x7FFF, N, off_n, is_n, csr_n);
  k_prescale<<<4096, 256, 0, stream>>>(nf, is_n, xb0, N);

  const int NB64 = (N + 63)/64;
  const int HB64 = (H + 63)/64;
  for (int l = 0; l < NLAYER; ++l){
    const float* hin = (l == 0) ? nf : Qb;
    const unsigned short* hsrc = (l == 0) ? xb0 : Qs;
    k_gather8<<<2048, 256, 0, stream>>>(hsrc, csr_h, off_h, aggxb, H);
    k_mmA<<<HB64, 256, 0, stream>>>(aggxb, Wag16 + l*4096, bn2h + l*64, is_h, hhsb, H);
    k_gather8<<<2048, 256, 0, stream>>>(hhsb, csr_n, off_n, agghb, N);
    k_fused<<<256, 1024, 0, stream>>>(agghb, Wbg16 + l*4096, bh2n + l*64, is_n, hin,
                                      g1 + l*64, be1 + l*64,
                                      W1g16 + l*64*256, b1 + l*256,
                                      W2g16 + l*256*64, b2 + l*64,
                                      g2 + l*64, be2 + l*64, Qb, Qs, N);
  }
  k_final<<<NB64, 256, 0, stream>>>(Qb, Wog16, bo, gF, bF, out, N);
}